// Round 1
// baseline (133.978 us; speedup 1.0000x reference)
//
#include <hip/hip_runtime.h>
#include <math.h>

#define TW 64
#define TH 16
#define RAW_W 77      // 74 used; stride 77 (odd) spreads banks
#define RAW_H 26      // TH + 10
#define HC_W 65       // 64 used; stride 65 spreads banks
#define NT 256
#define SSIM_C1 1e-4f
#define SSIM_C2 9e-4f

// Stage: depthwise separable 11x11 Gaussian conv (5 fields) + SSIM map + block reduce.
template <bool ATOMIC>
__global__ __launch_bounds__(NT, 1) void ssim_conv(
    const float* __restrict__ img1, const float* __restrict__ img2,
    const float* __restrict__ window, float* __restrict__ partials)
{
    __shared__ float raw1[RAW_H][RAW_W];
    __shared__ float raw2[RAW_H][RAW_W];
    __shared__ float hc[5][RAW_H][HC_W];
    __shared__ float wred[4];

    const int tid = threadIdx.x;
    const int x0 = blockIdx.x * TW;
    const int y0 = blockIdx.y * TH;
    const int plane = blockIdx.z;
    const float* p1 = img1 + (size_t)plane * 512 * 512;
    const float* p2 = img2 + (size_t)plane * 512 * 512;

    // 1D gaussian: window row 5 is g[5]*g[:], center w[5][5]=g[5]^2
    float g[11];
    {
        float r5 = rsqrtf(window[60]);
        #pragma unroll
        for (int j = 0; j < 11; ++j) g[j] = window[55 + j] * r5;
    }

    // ---- stage 1: raw tiles into LDS (zero pad outside plane, clip [0,1]) ----
    for (int l = tid; l < RAW_H * 74; l += NT) {
        int r  = l / 74;
        int cx = l - r * 74;
        int gy = y0 - 5 + r;
        int gx = x0 - 5 + cx;
        float a = 0.f, b = 0.f;
        if (gy >= 0 && gy < 512 && gx >= 0 && gx < 512) {
            int idx = gy * 512 + gx;
            a = p1[idx];
            b = p2[idx];
            a = fminf(fmaxf(a, 0.f), 1.f);
            b = fminf(fmaxf(b, 0.f), 1.f);
        }
        raw1[r][cx] = a;
        raw2[r][cx] = b;
    }
    __syncthreads();

    // ---- stage 2: horizontal conv, 4-wide x-slide per task ----
    // tasks: 26 rows x 16 xq = 416
    for (int l = tid; l < RAW_H * 16; l += NT) {
        int r     = l >> 4;
        int xbase = (l & 15) * 4;
        float h1[4]  = {0,0,0,0}, h2[4]  = {0,0,0,0};
        float h11[4] = {0,0,0,0}, h22[4] = {0,0,0,0}, h12[4] = {0,0,0,0};
        #pragma unroll
        for (int j = 0; j < 14; ++j) {
            float a = raw1[r][xbase + j];
            float b = raw2[r][xbase + j];
            float aa = a * a, bb = b * b, ab = a * b;
            #pragma unroll
            for (int i = 0; i < 4; ++i) {
                int k = j - i;
                if (k >= 0 && k < 11) {
                    float gk = g[k];
                    h1[i]  += gk * a;
                    h2[i]  += gk * b;
                    h11[i] += gk * aa;
                    h22[i] += gk * bb;
                    h12[i] += gk * ab;
                }
            }
        }
        #pragma unroll
        for (int i = 0; i < 4; ++i) {
            hc[0][r][xbase + i] = h1[i];
            hc[1][r][xbase + i] = h2[i];
            hc[2][r][xbase + i] = h11[i];
            hc[3][r][xbase + i] = h22[i];
            hc[4][r][xbase + i] = h12[i];
        }
    }
    __syncthreads();

    // ---- stage 3: vertical conv, 4-wide y-slide per thread + SSIM ----
    // tasks: 64 x-cols x 4 y-quads = 256 (one per thread)
    float lsum = 0.f;
    {
        int x     = tid & 63;
        int ybase = (tid >> 6) * 4;
        float m1[4]  = {0,0,0,0}, m2[4]  = {0,0,0,0};
        float e11[4] = {0,0,0,0}, e22[4] = {0,0,0,0}, e12[4] = {0,0,0,0};
        #pragma unroll
        for (int j = 0; j < 14; ++j) {
            float v0 = hc[0][ybase + j][x];
            float v1 = hc[1][ybase + j][x];
            float v2 = hc[2][ybase + j][x];
            float v3 = hc[3][ybase + j][x];
            float v4 = hc[4][ybase + j][x];
            #pragma unroll
            for (int i = 0; i < 4; ++i) {
                int k = j - i;
                if (k >= 0 && k < 11) {
                    float gk = g[k];
                    m1[i]  += gk * v0;
                    m2[i]  += gk * v1;
                    e11[i] += gk * v2;
                    e22[i] += gk * v3;
                    e12[i] += gk * v4;
                }
            }
        }
        #pragma unroll
        for (int i = 0; i < 4; ++i) {
            float mu1 = m1[i], mu2 = m2[i];
            float mu1sq = mu1 * mu1, mu2sq = mu2 * mu2, mu12 = mu1 * mu2;
            float s1  = e11[i] - mu1sq;
            float s2  = e22[i] - mu2sq;
            float s12 = e12[i] - mu12;
            float num = (2.f * mu12 + SSIM_C1) * (2.f * s12 + SSIM_C2);
            float den = (mu1sq + mu2sq + SSIM_C1) * (s1 + s2 + SSIM_C2);
            float v = num / den;
            v = fminf(fmaxf(v, 0.f), 1.f);
            lsum += v;
        }
    }

    // ---- block reduce ----
    #pragma unroll
    for (int off = 32; off > 0; off >>= 1) lsum += __shfl_down(lsum, off);
    if ((tid & 63) == 0) wred[tid >> 6] = lsum;
    __syncthreads();
    if (tid == 0) {
        float bsum = wred[0] + wred[1] + wred[2] + wred[3];
        int bid = (blockIdx.z * gridDim.y + blockIdx.y) * gridDim.x + blockIdx.x;
        if (ATOMIC) atomicAdd(&partials[0], bsum);
        else        partials[bid] = bsum;
    }
}

__global__ void ssim_finalize(const float* __restrict__ partials, int n,
                              float* __restrict__ out, float inv_npx)
{
    __shared__ float w[4];
    float s = 0.f;
    for (int i = threadIdx.x; i < n; i += 256) s += partials[i];
    #pragma unroll
    for (int off = 32; off > 0; off >>= 1) s += __shfl_down(s, off);
    if ((threadIdx.x & 63) == 0) w[threadIdx.x >> 6] = s;
    __syncthreads();
    if (threadIdx.x == 0) {
        float total = w[0] + w[1] + w[2] + w[3];
        float loss = 1.0f - total * inv_npx;
        out[0] = fmaxf(loss, 0.0f);
    }
}

extern "C" void kernel_launch(void* const* d_in, const int* in_sizes, int n_in,
                              void* d_out, int out_size, void* d_ws, size_t ws_size,
                              hipStream_t stream) {
    const float* img1   = (const float*)d_in[0];
    const float* img2   = (const float*)d_in[1];
    const float* window = (const float*)d_in[2];
    float* out      = (float*)d_out;
    float* partials = (float*)d_ws;

    int planes = in_sizes[0] >> 18;          // / (512*512) = 48
    dim3 grid(512 / TW, 512 / TH, planes);   // 8 x 32 x 48 = 12288 blocks
    int npart = grid.x * grid.y * grid.z;
    float inv_npx = 1.0f / (float)in_sizes[0];

    if (ws_size >= (size_t)npart * sizeof(float)) {
        ssim_conv<false><<<grid, NT, 0, stream>>>(img1, img2, window, partials);
        ssim_finalize<<<1, 256, 0, stream>>>(partials, npart, out, inv_npx);
    } else {
        hipMemsetAsync(d_ws, 0, sizeof(float), stream);
        ssim_conv<true><<<grid, NT, 0, stream>>>(img1, img2, window, partials);
        ssim_finalize<<<1, 256, 0, stream>>>(partials, 1, out, inv_npx);
    }
}

// Round 2
// 72.305 us; speedup vs baseline: 1.8530x; 1.8530x over previous
//
#include <hip/hip_runtime.h>
#include <math.h>

#define TW 64
#define TH 32
#define XH 74        // TW + 10 halo columns
#define VCW 76       // padded row stride (16B-multiple rows, bank-balanced)
#define NT 256
#define SSIM_C1 1e-4f
#define SSIM_C2 9e-4f

// Fused separable SSIM:
//   pass 1 (vertical, global->regs->LDS): per halo-column thread task, slide 8
//           outputs in y; 18 coalesced row loads; 5 fields convolved vertically.
//   pass 2 (horizontal, LDS b128->regs): per thread 8 consecutive x outputs,
//           aligned float4 reads of vc rows; 11-tap slide; SSIM epilogue; reduce.
template <bool ATOMIC>
__global__ __launch_bounds__(NT, 3) void ssim_fused(
    const float* __restrict__ img1, const float* __restrict__ img2,
    const float* __restrict__ window, float* __restrict__ partials)
{
    __shared__ float vc[5][TH][VCW];   // 5*32*76*4 = 48640 B
    __shared__ float wred[4];

    const int tid = threadIdx.x;
    const int x0 = blockIdx.x * TW;
    const int y0 = blockIdx.y * TH;
    const float* p1 = img1 + (size_t)blockIdx.z * (512 * 512);
    const float* p2 = img2 + (size_t)blockIdx.z * (512 * 512);

    // 1D gaussian from window row 5: w2[5][j] = g[5]*g[j], w2[5][5] = g[5]^2
    float g[11];
    {
        float r5 = rsqrtf(window[60]);
        #pragma unroll
        for (int j = 0; j < 11; ++j) g[j] = window[55 + j] * r5;
    }

    // ---- pass 1: vertical conv (74 cols x 4 y-octets = 296 tasks) ----
    for (int l = tid; l < XH * (TH / 8); l += NT) {
        int xh = l % XH;
        int yq = l / XH;
        int gx = x0 - 5 + xh;
        int yb = y0 + yq * 8;
        bool xok = (unsigned)gx < 512u;

        float ra[18], rb[18];
        #pragma unroll
        for (int j = 0; j < 18; ++j) {
            int gy = yb - 5 + j;
            float a = 0.f, b = 0.f;
            if (xok && (unsigned)gy < 512u) {
                int idx = gy * 512 + gx;
                a = p1[idx];
                b = p2[idx];
            }
            ra[j] = a; rb[j] = b;
        }

        float a0[8] = {0,0,0,0,0,0,0,0}, a1[8] = {0,0,0,0,0,0,0,0};
        float a2[8] = {0,0,0,0,0,0,0,0}, a3[8] = {0,0,0,0,0,0,0,0};
        float a4[8] = {0,0,0,0,0,0,0,0};
        #pragma unroll
        for (int j = 0; j < 18; ++j) {
            float a = ra[j], b = rb[j];
            float aa = a * a, bb = b * b, ab = a * b;
            #pragma unroll
            for (int i = 0; i < 8; ++i) {
                int k = j - i;
                if (k >= 0 && k < 11) {
                    float gk = g[k];
                    a0[i] += gk * a;  a1[i] += gk * b;
                    a2[i] += gk * aa; a3[i] += gk * bb; a4[i] += gk * ab;
                }
            }
        }
        int yb8 = yq * 8;
        #pragma unroll
        for (int i = 0; i < 8; ++i) {
            vc[0][yb8 + i][xh] = a0[i];
            vc[1][yb8 + i][xh] = a1[i];
            vc[2][yb8 + i][xh] = a2[i];
            vc[3][yb8 + i][xh] = a3[i];
            vc[4][yb8 + i][xh] = a4[i];
        }
    }
    __syncthreads();

    // ---- pass 2: horizontal conv + SSIM (64 cols as 8 octets x 32 rows) ----
    float lsum = 0.f;
    {
        int x8 = (tid & 7) * 8;   // output x octet base (local)
        int yl = tid >> 3;        // output row (local), 0..31
        float m[5][8];
        #pragma unroll
        for (int f = 0; f < 5; ++f) {
            const float* row = &vc[f][yl][x8];
            float4 q0 = *(const float4*)(row);
            float4 q1 = *(const float4*)(row + 4);
            float4 q2 = *(const float4*)(row + 8);
            float4 q3 = *(const float4*)(row + 12);
            float4 q4 = *(const float4*)(row + 16);
            float v[20] = {q0.x,q0.y,q0.z,q0.w, q1.x,q1.y,q1.z,q1.w,
                           q2.x,q2.y,q2.z,q2.w, q3.x,q3.y,q3.z,q3.w,
                           q4.x,q4.y,q4.z,q4.w};
            #pragma unroll
            for (int i = 0; i < 8; ++i) {
                float acc = 0.f;
                #pragma unroll
                for (int k = 0; k < 11; ++k) acc += g[k] * v[i + k];
                m[f][i] = acc;
            }
        }
        #pragma unroll
        for (int i = 0; i < 8; ++i) {
            float mu1 = m[0][i], mu2 = m[1][i];
            float mu1sq = mu1 * mu1, mu2sq = mu2 * mu2, mu12 = mu1 * mu2;
            float s1  = m[2][i] - mu1sq;
            float s2  = m[3][i] - mu2sq;
            float s12 = m[4][i] - mu12;
            float num = (2.f * mu12 + SSIM_C1) * (2.f * s12 + SSIM_C2);
            float den = (mu1sq + mu2sq + SSIM_C1) * (s1 + s2 + SSIM_C2);
            float v = num * __builtin_amdgcn_rcpf(den);
            lsum += fminf(fmaxf(v, 0.f), 1.f);
        }
    }

    // ---- block reduce ----
    #pragma unroll
    for (int off = 32; off > 0; off >>= 1) lsum += __shfl_down(lsum, off);
    if ((tid & 63) == 0) wred[tid >> 6] = lsum;
    __syncthreads();
    if (tid == 0) {
        float bsum = wred[0] + wred[1] + wred[2] + wred[3];
        int bid = (blockIdx.z * gridDim.y + blockIdx.y) * gridDim.x + blockIdx.x;
        if (ATOMIC) atomicAdd(&partials[0], bsum);
        else        partials[bid] = bsum;
    }
}

__global__ void ssim_finalize(const float* __restrict__ partials, int n,
                              float* __restrict__ out, float inv_npx)
{
    __shared__ float w[4];
    float s = 0.f;
    for (int i = threadIdx.x; i < n; i += 256) s += partials[i];
    #pragma unroll
    for (int off = 32; off > 0; off >>= 1) s += __shfl_down(s, off);
    if ((threadIdx.x & 63) == 0) w[threadIdx.x >> 6] = s;
    __syncthreads();
    if (threadIdx.x == 0) {
        float total = w[0] + w[1] + w[2] + w[3];
        float loss = 1.0f - total * inv_npx;
        out[0] = fmaxf(loss, 0.0f);
    }
}

extern "C" void kernel_launch(void* const* d_in, const int* in_sizes, int n_in,
                              void* d_out, int out_size, void* d_ws, size_t ws_size,
                              hipStream_t stream) {
    const float* img1   = (const float*)d_in[0];
    const float* img2   = (const float*)d_in[1];
    const float* window = (const float*)d_in[2];
    float* out      = (float*)d_out;
    float* partials = (float*)d_ws;

    int planes = in_sizes[0] >> 18;          // 48
    dim3 grid(512 / TW, 512 / TH, planes);   // 8 x 16 x 48 = 6144 blocks
    int npart = grid.x * grid.y * grid.z;
    float inv_npx = 1.0f / (float)in_sizes[0];

    if (ws_size >= (size_t)npart * sizeof(float)) {
        ssim_fused<false><<<grid, NT, 0, stream>>>(img1, img2, window, partials);
        ssim_finalize<<<1, 256, 0, stream>>>(partials, npart, out, inv_npx);
    } else {
        hipMemsetAsync(d_ws, 0, sizeof(float), stream);
        ssim_fused<true><<<grid, NT, 0, stream>>>(img1, img2, window, partials);
        ssim_finalize<<<1, 256, 0, stream>>>(partials, 1, out, inv_npx);
    }
}